// Round 8
// baseline (338.647 us; speedup 1.0000x reference)
//
#include <hip/hip_runtime.h>

typedef __bf16 bf16_t;
typedef __attribute__((ext_vector_type(8))) __bf16 bf16x8;
typedef __attribute__((ext_vector_type(4))) float f32x4;
typedef __attribute__((ext_vector_type(8))) unsigned short u16x8;

// async global->LDS DMA, 16B per lane; LDS dst linear in lane (base + lane*16)
__device__ __forceinline__ void dma16(const void* g, void* l) {
    __builtin_amdgcn_global_load_lds(
        reinterpret_cast<const unsigned int __attribute__((address_space(1)))*>(
            reinterpret_cast<unsigned long long>(g)),
        reinterpret_cast<unsigned int __attribute__((address_space(3)))*>(
            (unsigned int)reinterpret_cast<unsigned long long>(l)),
        16, 0, 0);
}

__device__ __forceinline__ float ldparam(const void* p, int i, int isbf) {
    return isbf ? (float)((const bf16_t*)p)[i] : ((const float*)p)[i];
}

// ---------------- dtype detect: 1 = bf16 inputs, 0 = fp32 inputs
__global__ void detect_dtype(const unsigned short* __restrict__ ct, int* __restrict__ flag) {
    if (threadIdx.x == 0 && blockIdx.x == 0) {
        int ok = 1;
        for (int i = 0; i < 16; i++) {
            int e = (ct[256 + i] >> 7) & 0xFF;
            ok &= (e >= 80 && e <= 126) ? 1 : 0;
        }
        *flag = ok;
    }
}

// ---------------- scan: partition rows; build parent map for write-through
__global__ void scan_rows(const int* __restrict__ lvl2, const int* __restrict__ lvl1,
                          const int* __restrict__ lvl0, const int* __restrict__ lch,
                          const int* __restrict__ rch, const int* __restrict__ tch,
                          int* __restrict__ lists, int* __restrict__ cnts,
                          unsigned* __restrict__ par) {
    int r = blockIdx.x * 256 + threadIdx.x;   // grid covers exactly 28672
    int slot, lr, base_t, base_b;
    const int* lvl;
    if (r < 16384)      { slot = 0; lr = r;         lvl = lvl2; base_t = 0;     base_b = 16384; }
    else if (r < 24576) { slot = 1; lr = r - 16384; lvl = lvl1; base_t = 32768; base_b = 40960; }
    else                { slot = 2; lr = r - 24576; lvl = lvl0; base_t = 49152; base_b = 53248; }
    int node = lvl[lr];
    int tern = tch[node] >= 0 ? 1 : 0;

    unsigned long long bt = __ballot(tern);
    unsigned long long bb = __ballot(!tern);
    int lane = threadIdx.x & 63;
    unsigned long long ltm = (1ull << lane) - 1ull;
    int post = __popcll(bt & ltm), posb = __popcll(bb & ltm);
    int baseT = 0, baseB = 0;
    if (lane == 0) {
        baseT = atomicAdd(&cnts[slot * 2 + 1], __popcll(bt));
        baseB = atomicAdd(&cnts[slot * 2 + 0], __popcll(bb));
    }
    baseT = __shfl(baseT, 0, 64);
    baseB = __shfl(baseB, 0, 64);
    int idx_in = tern ? (baseT + post) : (baseB + posb);
    lists[(tern ? base_t : base_b) + idx_in] = lr;
    if (slot >= 1) {  // this row's children (next level down) write through into our A-row
        unsigned enc = ((unsigned)tern << 31) | ((unsigned)idx_in << 2);
        par[lch[node]] = enc | 0u;
        par[rch[node]] = enc | 1u;
        if (tern) par[tch[node]] = enc | 2u;
    }
}

// ---------------- pack weights (children rows only) -> [kc][n][32] bf16
__global__ void pack_all(const void* __restrict__ W1t, const void* __restrict__ W1b,
                         const void* __restrict__ W2t, const void* __restrict__ W2b,
                         bf16_t* __restrict__ W1tf, bf16_t* __restrict__ W1bf,
                         bf16_t* __restrict__ W2tf, bf16_t* __restrict__ W2bf,
                         const int* __restrict__ flagp) {
    int e = blockIdx.x * 256 + threadIdx.x;
    int isbf = *flagp;
    if (e < 393216) {              // W1t children: 768 x 512
        int k = e >> 9, n = e & 511, si = (k + 256) * 512 + n;
        bf16_t v = isbf ? ((const bf16_t*)W1t)[si] : (bf16_t)((const float*)W1t)[si];
        W1tf[(size_t)(((k >> 5) * 512 + n) * 32 + (k & 31))] = v;
    } else if (e < 655360) {       // W1b children: 512 x 512
        int e2 = e - 393216, k = e2 >> 9, n = e2 & 511, si = (k + 256) * 512 + n;
        bf16_t v = isbf ? ((const bf16_t*)W1b)[si] : (bf16_t)((const float*)W1b)[si];
        W1bf[(size_t)(((k >> 5) * 512 + n) * 32 + (k & 31))] = v;
    } else if (e < 786432) {       // W2t: 512 x 256
        int e2 = e - 655360, k = e2 >> 8, n = e2 & 255, si = k * 256 + n;
        bf16_t v = isbf ? ((const bf16_t*)W2t)[si] : (bf16_t)((const float*)W2t)[si];
        W2tf[(size_t)(((k >> 5) * 256 + n) * 32 + (k & 31))] = v;
    } else if (e < 917504) {       // W2b
        int e2 = e - 786432, k = e2 >> 8, n = e2 & 255, si = k * 256 + n;
        bf16_t v = isbf ? ((const bf16_t*)W2b)[si] : (bf16_t)((const float*)W2b)[si];
        W2bf[(size_t)(((k >> 5) * 256 + n) * 32 + (k & 31))] = v;
    }
}

// ---------------- opbias[type][16][512] = op_table @ W1[0:256,:] + b1 (exact fp32)
__global__ void opbias_k(const void* __restrict__ op,
                         const void* __restrict__ W1t, const void* __restrict__ W1b,
                         const void* __restrict__ b1t, const void* __restrict__ b1b,
                         float* __restrict__ obt, float* __restrict__ obb,
                         const int* __restrict__ flagp) {
    __shared__ float opr[256];
    int b = blockIdx.x, isbf = *flagp;
    int typ = b >> 4, o = b & 15;
    const void* W = typ ? W1t : W1b;
    const void* bb = typ ? b1t : b1b;
    float* ob = typ ? obt : obb;
    opr[threadIdx.x] = ldparam(op, o * 256 + threadIdx.x, isbf);
    __syncthreads();
    int n0 = threadIdx.x, n1 = threadIdx.x + 256;
    float a0 = 0.f, a1 = 0.f;
    for (int k = 0; k < 256; k++) {
        float ov = opr[k];
        a0 += ov * ldparam(W, k * 512 + n0, isbf);
        a1 += ov * ldparam(W, k * 512 + n1, isbf);
    }
    ob[o * 512 + n0] = a0 + ldparam(bb, n0, isbf);
    ob[o * 512 + n1] = a1 + ldparam(bb, n1, isbf);
}

// ---------------- leaf gather: build lvl2 A-rows = concat(le,re[,te]) from comp_table
__global__ void leaf_gather(const int* __restrict__ lists, const int* __restrict__ cnts,
                            const int* __restrict__ lvl2, const int* __restrict__ lch,
                            const int* __restrict__ rch, const int* __restrict__ tch,
                            const int* __restrict__ cid, const void* __restrict__ ct,
                            const int* __restrict__ flagp,
                            bf16_t* __restrict__ A2t, bf16_t* __restrict__ A2b) {
    int e = blockIdx.x * 256 + threadIdx.x;
    int isbf = *flagp;
    int row, ch, K;
    const int* list; bf16_t* dst;
    if (e < 16384 * 96) { row = e / 96; ch = e - row * 96; if (row >= cnts[1]) return;
                          list = lists; dst = A2t; K = 768; }
    else { e -= 16384 * 96; row = e >> 6; ch = e & 63; if (row >= cnts[0]) return;
           list = lists + 16384; dst = A2b; K = 512; }
    int nd = lvl2[list[row]];
    int colg = ch * 8, piece = colg >> 8, po = colg & 255;
    int child = piece == 0 ? lch[nd] : (piece == 1 ? rch[nd] : tch[nd]);
    int cp = cid[child];
    bf16_t* d = dst + (size_t)row * K + colg;
    if (isbf) {
        *(u16x8*)d = *(const u16x8*)((const unsigned short*)ct + (size_t)cp * 256 + po);
    } else {
        const float* fp = (const float*)ct + (size_t)cp * 256 + po;
        bf16_t t8[8];
        for (int z = 0; z < 8; z++) t8[z] = (bf16_t)fp[z];
        *(u16x8*)d = *(u16x8*)t8;
    }
}

// ---------------- GEMM1: A[rows x K] @ W1 -> GELU(+opbias) -> H   (BM=128, BN=128, BK=32)
__global__ __launch_bounds__(256, 2) void gemm1(
    const int* __restrict__ list_t, const int* __restrict__ list_b,
    const int* __restrict__ cntpair, const int* __restrict__ lvl_idx,
    const int* __restrict__ op_ids,
    const bf16_t* __restrict__ At, const bf16_t* __restrict__ Ab,
    const bf16_t* __restrict__ W1tf, const bf16_t* __restrict__ W1bf,
    const float* __restrict__ obt, const float* __restrict__ obb,
    bf16_t* __restrict__ H)
{
    __shared__ __align__(16) unsigned short Ash[4096];  // [128][32]
    __shared__ __align__(16) unsigned short Bsh[4096];  // [128][32]
    __shared__ int opRowL[128];

    const int tid = threadIdx.x;
    const int cnt_t = cntpair[1], cnt_b = cntpair[0];
    const int nbt = (cnt_t + 127) >> 7;
    int cb = blockIdx.x >> 2;
    const int Nb = blockIdx.x & 3;
    int tern, Mb, cnt, K, Kc;
    const int* list; const bf16_t *Ar, *Wf; const float* obp; bf16_t* Hp;
    if (cb < nbt) {
        tern = 1; list = list_t; Mb = cb << 7; cnt = cnt_t; K = 768; Kc = 24;
        Ar = At; Wf = W1tf; obp = obt; Hp = H;
    } else {
        cb -= nbt; Mb = cb << 7; cnt = cnt_b;
        if (Mb >= cnt) return;
        tern = 0; list = list_b; K = 512; Kc = 16;
        Ar = Ab; Wf = W1bf; obp = obb; Hp = H + (size_t)16384 * 512;
    }
    const int act = min(128, cnt - Mb);
    if (tid < 128) opRowL[tid] = op_ids[lvl_idx[list[Mb + min(tid, act - 1)]]];

    const int w = tid >> 6, lane = tid & 63, cc = lane & 15, qq = lane >> 4;
    const int wm = w >> 1, wn = w & 1;

    const f32x4 zf = {0.f, 0.f, 0.f, 0.f};
    f32x4 acc[4][4];
#pragma unroll
    for (int mi = 0; mi < 4; mi++) for (int ji = 0; ji < 4; ji++) acc[mi][ji] = zf;

    for (int kc = 0; kc < Kc; kc++) {
        __syncthreads();
#pragma unroll
        for (int s = 0; s < 2; s++) {
            int idx = s * 256 + tid;
            int row = idx >> 2, c4 = idx & 3;
            dma16(Ar + (size_t)(Mb + row) * K + kc * 32 + c4 * 8, (char*)Ash + idx * 16);
            dma16(Wf + ((size_t)kc * 512 + (Nb << 7) + row) * 32 + c4 * 8, (char*)Bsh + idx * 16);
        }
        __syncthreads();
        bf16x8 af[4], bfv[4];
#pragma unroll
        for (int mi = 0; mi < 4; mi++)
            af[mi] = *(const bf16x8*)((const bf16_t*)Ash + (wm * 64 + mi * 16 + cc) * 32 + qq * 8);
#pragma unroll
        for (int ji = 0; ji < 4; ji++)
            bfv[ji] = *(const bf16x8*)((const bf16_t*)Bsh + (wn * 64 + ji * 16 + cc) * 32 + qq * 8);
#pragma unroll
        for (int ji = 0; ji < 4; ji++)
#pragma unroll
            for (int mi = 0; mi < 4; mi++)
                acc[mi][ji] = __builtin_amdgcn_mfma_f32_16x16x32_bf16(af[mi], bfv[ji], acc[mi][ji], 0, 0, 0);
    }

    // epilogue: opbias + exact GELU -> H (list-order rows)
#pragma unroll
    for (int ji = 0; ji < 4; ji++) {
        int col = (Nb << 7) + wn * 64 + ji * 16 + cc;
#pragma unroll
        for (int mi = 0; mi < 4; mi++) for (int r = 0; r < 4; r++) {
            int row = wm * 64 + mi * 16 + qq * 4 + r;
            float v = acc[mi][ji][r] + obp[opRowL[row] * 512 + col];
            float h = 0.5f * v * (1.0f + erff(v * 0.70710678118654752f));
            Hp[(size_t)(Mb + row) * 512 + col] = (bf16_t)h;
        }
    }
}

// ---------------- GEMM2: H @ W2 + b2 + residual -> LN -> scatter (BM=64, BN=256)
__global__ __launch_bounds__(256, 2) void gemm2(
    const int* __restrict__ list_t, const int* __restrict__ list_b,
    const int* __restrict__ cntpair, const int* __restrict__ lvl_idx,
    const unsigned* __restrict__ par, const int* __restrict__ flagp,
    const bf16_t* __restrict__ At, const bf16_t* __restrict__ Ab,
    const bf16_t* __restrict__ W2tf, const bf16_t* __restrict__ W2bf,
    const void* __restrict__ b2t, const void* __restrict__ b2b,
    const void* __restrict__ gma, const void* __restrict__ bta,
    const bf16_t* __restrict__ H,
    bf16_t* __restrict__ Ant, bf16_t* __restrict__ Anb, void* __restrict__ outp)
{
    __shared__ __align__(16) char U[69632];
    unsigned short* Ash = (unsigned short*)U;            // [64][32]  (GEMM phase)
    unsigned short* Bsh = (unsigned short*)(U + 4096);   // [256][32] (GEMM phase)
    float* Rf    = (float*)U;                            // [64][260] (epilogue)
    float* partS = (float*)(U + 66560);
    float* partQ = (float*)(U + 67584);
    float* muA   = (float*)(U + 68608);
    float* rsA   = (float*)(U + 68864);
    int*   lrA   = (int*)(U + 69120);
    unsigned* parA = (unsigned*)(U + 69376);

    const int tid = threadIdx.x;
    const int cnt_t = cntpair[1], cnt_b = cntpair[0];
    const int nbt = (cnt_t + 63) >> 6;
    int cb = blockIdx.x;
    int tern, Mb, cnt, K;
    const int* list; const bf16_t *Ar, *Wf, *Hsrc; const void* b2;
    if (cb < nbt) {
        tern = 1; list = list_t; Mb = cb << 6; cnt = cnt_t; K = 768;
        Ar = At; Wf = W2tf; b2 = b2t; Hsrc = H;
    } else {
        cb -= nbt; Mb = cb << 6; cnt = cnt_b;
        if (Mb >= cnt) return;
        tern = 0; list = list_b; K = 512;
        Ar = Ab; Wf = W2bf; b2 = b2b; Hsrc = H + (size_t)16384 * 512;
    }
    const int act = min(64, cnt - Mb);
    const int isbf = *flagp;

    if (tid < 64) {
        int lr = list[Mb + min(tid, act - 1)];
        lrA[tid] = lr;
        parA[tid] = outp ? 0u : par[lvl_idx[lr]];
    }

    const int w = tid >> 6, lane = tid & 63, cc = lane & 15, qq = lane >> 4;
    const f32x4 zf = {0.f, 0.f, 0.f, 0.f};
    f32x4 acc[4][4];
#pragma unroll
    for (int mi = 0; mi < 4; mi++) for (int ji = 0; ji < 4; ji++) acc[mi][ji] = zf;

    for (int kc = 0; kc < 16; kc++) {
        __syncthreads();
        {
            int row = tid >> 2, c4 = tid & 3;
            dma16(Hsrc + (size_t)(Mb + row) * 512 + kc * 32 + c4 * 8, (char*)Ash + tid * 16);
        }
#pragma unroll
        for (int s = 0; s < 4; s++) {
            int idx = s * 256 + tid;
            int n = idx >> 2, c4 = idx & 3;
            dma16(Wf + ((size_t)kc * 256 + n) * 32 + c4 * 8, (char*)Bsh + idx * 16);
        }
        __syncthreads();
        bf16x8 af[4], bfv[4];
#pragma unroll
        for (int mi = 0; mi < 4; mi++)
            af[mi] = *(const bf16x8*)((const bf16_t*)Ash + (mi * 16 + cc) * 32 + qq * 8);
#pragma unroll
        for (int ji = 0; ji < 4; ji++)
            bfv[ji] = *(const bf16x8*)((const bf16_t*)Bsh + (w * 64 + ji * 16 + cc) * 32 + qq * 8);
#pragma unroll
        for (int ji = 0; ji < 4; ji++)
#pragma unroll
            for (int mi = 0; mi < 4; mi++)
                acc[mi][ji] = __builtin_amdgcn_mfma_f32_16x16x32_bf16(af[mi], bfv[ji], acc[mi][ji], 0, 0, 0);
    }
    __syncthreads();   // GEMM LDS reads done before Rf overwrites

    // residual: Rf[64][260] from this level's A-rows (contiguous)
    {
        int rr = tid >> 2, q4 = tid & 3;
        int rmin = min(rr, act - 1);
        const bf16_t* base = Ar + (size_t)(Mb + rmin) * K;
        float scale = tern ? (1.0f / 3.0f) : 1.0f;
        for (int j = 0; j < 8; j++) {
            int q = q4 * 64 + j * 8;
            bf16x8 a = *(const bf16x8*)(base + q);
            bf16x8 b = *(const bf16x8*)(base + 256 + q);
            float s[8];
            for (int z = 0; z < 8; z++) s[z] = (float)a[z] + (float)b[z];
            if (tern) {
                bf16x8 c = *(const bf16x8*)(base + 512 + q);
                for (int z = 0; z < 8; z++) s[z] += (float)c[z];
            }
            f32x4 o0, o1;
            for (int z = 0; z < 4; z++) { o0[z] = s[z] * scale; o1[z] = s[z + 4] * scale; }
            *(f32x4*)(Rf + rr * 260 + q) = o0;
            *(f32x4*)(Rf + rr * 260 + q + 4) = o1;
        }
    }
    __syncthreads();

    // x = acc + b2 + R ; LayerNorm over 256 cols
    float b2f[4], gf[4], btf[4];
#pragma unroll
    for (int ji = 0; ji < 4; ji++) {
        int col = w * 64 + ji * 16 + cc;
        b2f[ji] = ldparam(b2, col, isbf);
        gf[ji] = ldparam(gma, col, isbf);
        btf[ji] = ldparam(bta, col, isbf);
    }
#pragma unroll
    for (int mi = 0; mi < 4; mi++) for (int r = 0; r < 4; r++) {
        int row = mi * 16 + qq * 4 + r;
        float ps = 0.f, pq = 0.f;
#pragma unroll
        for (int ji = 0; ji < 4; ji++) {
            int col = w * 64 + ji * 16 + cc;
            float x = acc[mi][ji][r] + b2f[ji] + Rf[row * 260 + col];
            acc[mi][ji][r] = x;
            ps += x; pq += x * x;
        }
        for (int d = 1; d < 16; d <<= 1) {
            ps += __shfl_xor(ps, d, 64);
            pq += __shfl_xor(pq, d, 64);
        }
        if (cc == 0) { partS[w * 64 + row] = ps; partQ[w * 64 + row] = pq; }
    }
    __syncthreads();
    if (tid < 64) {
        float s  = partS[tid] + partS[64 + tid] + partS[128 + tid] + partS[192 + tid];
        float sq = partQ[tid] + partQ[64 + tid] + partQ[128 + tid] + partQ[192 + tid];
        float mu = s * (1.0f / 256.0f);
        float var = sq * (1.0f / 256.0f) - mu * mu;
        muA[tid] = mu;
        rsA[tid] = rsqrtf(fmaxf(var, 0.0f) + 1e-5f);
    }
    __syncthreads();

#pragma unroll
    for (int mi = 0; mi < 4; mi++) for (int r = 0; r < 4; r++) {
        int row = mi * 16 + qq * 4 + r;
        if (row >= act) continue;
        float mu = muA[row], rs = rsA[row];
#pragma unroll
        for (int ji = 0; ji < 4; ji++) {
            int col = w * 64 + ji * 16 + cc;
            float y = (acc[mi][ji][r] - mu) * rs * gf[ji] + btf[ji];
            if (outp) {
                size_t o = (size_t)lrA[row] * 256 + col;
                if (isbf) ((bf16_t*)outp)[o] = (bf16_t)y;
                else      ((float*)outp)[o] = y;
            } else {
                unsigned pr = parA[row];
                int bkt = pr >> 31, prow = (pr >> 2) & 0x3FFF, pc = pr & 3;
                bf16_t* dst = bkt ? Ant : Anb;
                int Kn = bkt ? 768 : 512;
                dst[(size_t)prow * Kn + pc * 256 + col] = (bf16_t)y;
            }
        }
    }
}

extern "C" void kernel_launch(void* const* d_in, const int* in_sizes, int n_in,
                              void* d_out, int out_size, void* d_ws, size_t ws_size,
                              hipStream_t stream) {
    const int* cid    = (const int*)d_in[0];
    const int* opids  = (const int*)d_in[1];
    const int* lch    = (const int*)d_in[2];
    const int* rch    = (const int*)d_in[3];
    const int* tch    = (const int*)d_in[4];
    const int* lvl2   = (const int*)d_in[5];
    const int* lvl1   = (const int*)d_in[6];
    const int* lvl0   = (const int*)d_in[7];
    const void* comp_table = d_in[8];
    const void* op_table   = d_in[9];
    const void* W1b = d_in[10];
    const void* b1b = d_in[11];
    const void* W2b = d_in[12];
    const void* b2b = d_in[13];
    const void* W1t = d_in[14];
    const void* b1t = d_in[15];
    const void* W2t = d_in[16];
    const void* b2t = d_in[17];
    const void* gma = d_in[18];
    const void* bta = d_in[19];

    char* wsp = (char*)d_ws;
    bf16_t* A2t = (bf16_t*)wsp;                  size_t off = 25165824; // 16384*768*2
    bf16_t* A2b = (bf16_t*)(wsp + off);          off += 16777216;       // 16384*512*2
    bf16_t* A1t = (bf16_t*)(wsp + off);          off += 12582912;       // 8192*768*2
    bf16_t* A1b = (bf16_t*)(wsp + off);          off += 8388608;        // 8192*512*2
    bf16_t* A0t = (bf16_t*)(wsp + off);          off += 6291456;        // 4096*768*2
    bf16_t* A0b = (bf16_t*)(wsp + off);          off += 4194304;        // 4096*512*2
    bf16_t* H   = (bf16_t*)(wsp + off);          off += 33554432;       // 32768*512*2
    bf16_t* W1tf = (bf16_t*)(wsp + off);         off += 786432;
    bf16_t* W1bf = (bf16_t*)(wsp + off);         off += 524288;
    bf16_t* W2tf = (bf16_t*)(wsp + off);         off += 262144;
    bf16_t* W2bf = (bf16_t*)(wsp + off);         off += 262144;
    float* obt   = (float*)(wsp + off);          off += 32768;
    float* obb   = (float*)(wsp + off);          off += 32768;
    int* lists   = (int*)(wsp + off);            off += 229376;
    unsigned* par = (unsigned*)(wsp + off);      off += 262144;
    int* cnts    = (int*)(wsp + off);            off += 64;             // ~109.4 MB
    int* flag    = cnts + 8;

    hipMemsetAsync(cnts, 0, 64, stream);
    detect_dtype<<<1, 64, 0, stream>>>((const unsigned short*)comp_table, flag);
    scan_rows<<<112, 256, 0, stream>>>(lvl2, lvl1, lvl0, lch, rch, tch, lists, cnts, par);
    pack_all<<<3584, 256, 0, stream>>>(W1t, W1b, W2t, W2b, W1tf, W1bf, W2tf, W2bf, flag);
    opbias_k<<<32, 256, 0, stream>>>(op_table, W1t, W1b, b1t, b1b, obt, obb, flag);
    leaf_gather<<<10240, 256, 0, stream>>>(lists, cnts, lvl2, lch, rch, tch, cid,
                                           comp_table, flag, A2t, A2b);

    // level 2
    gemm1<<<516, 256, 0, stream>>>(lists + 0, lists + 16384, cnts + 0, lvl2, opids,
        A2t, A2b, W1tf, W1bf, obt, obb, H);
    gemm2<<<258, 256, 0, stream>>>(lists + 0, lists + 16384, cnts + 0, lvl2, par, flag,
        A2t, A2b, W2tf, W2bf, b2t, b2b, gma, bta, H, A1t, A1b, nullptr);
    // level 1
    gemm1<<<260, 256, 0, stream>>>(lists + 32768, lists + 40960, cnts + 2, lvl1, opids,
        A1t, A1b, W1tf, W1bf, obt, obb, H);
    gemm2<<<130, 256, 0, stream>>>(lists + 32768, lists + 40960, cnts + 2, lvl1, par, flag,
        A1t, A1b, W2tf, W2bf, b2t, b2b, gma, bta, H, A0t, A0b, nullptr);
    // level 0 -> d_out
    gemm1<<<132, 256, 0, stream>>>(lists + 49152, lists + 53248, cnts + 4, lvl0, opids,
        A0t, A0b, W1tf, W1bf, obt, obb, H);
    gemm2<<<66, 256, 0, stream>>>(lists + 49152, lists + 53248, cnts + 4, lvl0, par, flag,
        A0t, A0b, W2tf, W2bf, b2t, b2b, gma, bta, H, nullptr, nullptr, d_out);
}